// Round 5
// baseline (707.113 us; speedup 1.0000x reference)
//
#include <hip/hip_runtime.h>

#define NN 100000
#define EE 1250000
#define HH 64
#define BB 256
#define CC 2
#define NBLK 391                   // ceil(NN/256)
#define CS ((size_t)NN * 8)        // floats per feature-chunk
#define GEMM_BLK 2048
#define GEMM_WAVES (GEMM_BLK * 4)
#define GATH_BLK 16384
#define WPC ((GATH_BLK / 8) * 4)   // waves per chunk = 8192
#define NPAIR (NN / 2)

__device__ __forceinline__ float lanebcast(float v, int k) {
    return __int_as_float(__builtin_amdgcn_readlane(__float_as_int(v), k));
}

// ---------------------------------------------------------------------------
// Index dtype detection (int64 vs int32): int64 values < 2^31 -> odd words 0
// ---------------------------------------------------------------------------
__global__ void detect_i64(const int* __restrict__ raw, int* __restrict__ flag) {
    __shared__ int nonzero;
    if (threadIdx.x == 0) nonzero = 0;
    __syncthreads();
    int any = 0;
#pragma unroll
    for (int i = 0; i < 4; ++i) {
        int idx = 2 * (threadIdx.x + i * 256) + 1;
        if (raw[idx] != 0) any = 1;
    }
    if (any) atomicOr(&nonzero, 1);
    __syncthreads();
    if (threadIdx.x == 0) *flag = nonzero ? 0 : 1;   // 1 => int64
}

// ---------------------------------------------------------------------------
// CSR build
// ---------------------------------------------------------------------------
__global__ void count_kernel(const int* __restrict__ raw, const int* __restrict__ flag,
                             int* __restrict__ degi) {
    int e = blockIdx.x * 256 + threadIdx.x;
    if (e >= EE) return;
    int d = (*flag) ? raw[2 * (EE + e)] : raw[EE + e];
    atomicAdd(&degi[d], 1);
}

__global__ __launch_bounds__(256) void scan1(const int* __restrict__ degi,
                                             int* __restrict__ row,
                                             int* __restrict__ bsum,
                                             float* __restrict__ dinv) {
    __shared__ int s[256];
    int tid = threadIdx.x;
    int n = blockIdx.x * 256 + tid;
    int v = (n < NN) ? degi[n] : 0;
    int x = v;
    s[tid] = x;
    __syncthreads();
    for (int off = 1; off < 256; off <<= 1) {
        int t = (tid >= off) ? s[tid - off] : 0;
        __syncthreads();
        x += t;
        s[tid] = x;
        __syncthreads();
    }
    if (n < NN) {
        row[n] = x - v;
        dinv[n] = rsqrtf((float)v + 1.0f);
    }
    if (tid == 255) bsum[blockIdx.x] = x;
}

__global__ __launch_bounds__(512) void scan2(int* __restrict__ bsum) {
    __shared__ int s[512];
    int tid = threadIdx.x;
    int v = (tid < NBLK) ? bsum[tid] : 0;
    int x = v;
    s[tid] = x;
    __syncthreads();
    for (int off = 1; off < 512; off <<= 1) {
        int t = (tid >= off) ? s[tid - off] : 0;
        __syncthreads();
        x += t;
        s[tid] = x;
        __syncthreads();
    }
    if (tid < NBLK) bsum[tid] = x - v;
}

__global__ void scan3(int* __restrict__ row, const int* __restrict__ bsum) {
    int n = blockIdx.x * 256 + threadIdx.x;
    if (n < NN) row[n] += bsum[blockIdx.x];
    if (n == 0) row[NN] = EE;
}

// counting sort: only src index stored (norm recomputed from dinv in gather)
__global__ void fill_kernel(const int* __restrict__ raw, const int* __restrict__ flag,
                            const int* __restrict__ row, int* __restrict__ fill,
                            int* __restrict__ esrc) {
    int e = blockIdx.x * 256 + threadIdx.x;
    if (e >= EE) return;
    int flg = *flag;
    int s = flg ? raw[2 * e]        : raw[e];
    int d = flg ? raw[2 * (EE + e)] : raw[EE + e];
    int pos = row[d] + atomicAdd(&fill[d], 1);
    esrc[pos] = s;
}

// ---------------------------------------------------------------------------
// G = dinv .* (X @ W), written in chunk-major layout [8][NN][8].
// IN_ROW=1: X row-major [NN][64]; IN_ROW=0: X chunk-major.
// One wave per row; W column in 64 VGPRs; readlane broadcast.
// ---------------------------------------------------------------------------
template <int IN_ROW>
__global__ __launch_bounds__(256) void gemm_scaled(
        const float* __restrict__ X, const float* __restrict__ W,
        const float* __restrict__ dinv, float* __restrict__ Gout) {
    int lane = threadIdx.x & 63;
    int gw = (blockIdx.x * 256 + threadIdx.x) >> 6;
    float Wreg[64];
#pragma unroll
    for (int k = 0; k < 64; ++k) Wreg[k] = W[k * 64 + lane];
    int c = lane >> 3, fl = lane & 7;
    for (int n = gw; n < NN; n += GEMM_WAVES) {
        int nu = __builtin_amdgcn_readfirstlane(n);
        float xv;
        if constexpr (IN_ROW)
            xv = __builtin_nontemporal_load(X + (size_t)nu * 64 + lane);
        else
            xv = __builtin_nontemporal_load(X + (size_t)c * CS + (size_t)nu * 8 + fl);
        float a0 = 0.f, a1 = 0.f;
#pragma unroll
        for (int k = 0; k < 64; k += 2) {
            a0 = fmaf(lanebcast(xv, k),     Wreg[k],     a0);
            a1 = fmaf(lanebcast(xv, k + 1), Wreg[k + 1], a1);
        }
        float r = (a0 + a1) * dinv[nu];
        __builtin_nontemporal_store(r, Gout + (size_t)c * CS + (size_t)nu * 8 + fl);
    }
}

// ---------------------------------------------------------------------------
// XCD-sharded gather. chunk = blockIdx&7 (round-robin -> one chunk per XCD;
// chunk working set 3.2MB G + 0.4MB dinv stays L2-resident).
// Wave layout: lane = edge_sub(8) x feat(8); 2 nodes per wave-iteration.
// out = dinv_n * (sum_e G[src] + G[n]) + bias  [; relu]
// ---------------------------------------------------------------------------
template <int RELU>
__global__ __launch_bounds__(256) void gather_chunk(
        const int* __restrict__ row, const int* __restrict__ esrc,
        const float* __restrict__ G, const float* __restrict__ dinv,
        const float* __restrict__ bias, float* __restrict__ Out) {
    int lane = threadIdx.x & 63;
    int chunk = blockIdx.x & 7;
    int wv = ((blockIdx.x >> 3) << 2) + (threadIdx.x >> 6);
    int fl = lane & 7, eg = lane >> 3;
    const float* __restrict__ Gc = G + (size_t)chunk * CS;
    float bv = bias[chunk * 8 + fl];

    for (int p = wv; p < NPAIR; p += WPC) {
        int nu = __builtin_amdgcn_readfirstlane(p) * 2;
        int b0 = row[nu], m = row[nu + 1], e1 = row[nu + 2];

        float acc0 = 0.f;
        for (int base = b0; base < m; base += 16) {
            int v0 = base + eg, v1 = v0 + 8;
            int c0 = v0 < m ? v0 : m - 1;
            int c1 = v1 < m ? v1 : m - 1;
            int s0 = __builtin_nontemporal_load(esrc + c0);
            int s1 = __builtin_nontemporal_load(esrc + c1);
            float g0 = Gc[(size_t)s0 * 8 + fl];
            float g1 = Gc[(size_t)s1 * 8 + fl];
            acc0 += (v0 < m ? g0 : 0.f) + (v1 < m ? g1 : 0.f);
        }
        float acc1 = 0.f;
        for (int base = m; base < e1; base += 16) {
            int v0 = base + eg, v1 = v0 + 8;
            int c0 = v0 < e1 ? v0 : e1 - 1;
            int c1 = v1 < e1 ? v1 : e1 - 1;
            int s0 = __builtin_nontemporal_load(esrc + c0);
            int s1 = __builtin_nontemporal_load(esrc + c1);
            float g0 = Gc[(size_t)s0 * 8 + fl];
            float g1 = Gc[(size_t)s1 * 8 + fl];
            acc1 += (v0 < e1 ? g0 : 0.f) + (v1 < e1 ? g1 : 0.f);
        }

        acc0 += __shfl_xor(acc0, 8, 64);
        acc0 += __shfl_xor(acc0, 16, 64);
        acc0 += __shfl_xor(acc0, 32, 64);
        acc1 += __shfl_xor(acc1, 8, 64);
        acc1 += __shfl_xor(acc1, 16, 64);
        acc1 += __shfl_xor(acc1, 32, 64);

        float d0 = dinv[nu], d1 = dinv[nu + 1];
        float gs0 = Gc[(size_t)nu * 8 + fl];
        float gs1 = Gc[(size_t)(nu + 1) * 8 + fl];
        // out = dinv_n * (Sigma G[src] + G[n]) + bias
        float o0 = fmaf(acc0 + gs0, d0, bv);
        float o1 = fmaf(acc1 + gs1, d1, bv);
        if constexpr (RELU) { o0 = fmaxf(o0, 0.f); o1 = fmaxf(o1, 0.f); }
        if (lane < 16) {
            float ov = (lane < 8) ? o0 : o1;
            __builtin_nontemporal_store(
                ov, Out + (size_t)chunk * CS + (size_t)(nu + (lane >> 3)) * 8 + fl);
        }
    }
}

// ---------------------------------------------------------------------------
// Mean pool (batch sorted, chunk-major input) + final linear
// ---------------------------------------------------------------------------
__global__ __launch_bounds__(256) void pool_kernel(
        const float* __restrict__ Hc, const int* __restrict__ braw,
        const int* __restrict__ flag,
        float* __restrict__ pooled, float* __restrict__ cnt) {
    int tid = threadIdx.x;
    int f = tid & 63, sub = tid >> 6;
    int c = f >> 3, fl = f & 7;
    int flg = *flag;
    int base = blockIdx.x * 256 + sub * 64;
    float acc = 0.0f;
    int cur = -1, count = 0;
    for (int i = 0; i < 64; ++i) {
        int n = base + i;
        if (n >= NN) break;
        int g = flg ? braw[2 * n] : braw[n];
        if (g != cur) {
            if (cur >= 0) {
                atomicAdd(&pooled[cur * 64 + f], acc);
                if (f == 0) atomicAdd(&cnt[cur], (float)count);
            }
            cur = g; acc = 0.0f; count = 0;
        }
        acc += Hc[(size_t)c * CS + (size_t)n * 8 + fl];
        ++count;
    }
    if (cur >= 0) {
        atomicAdd(&pooled[cur * 64 + f], acc);
        if (f == 0) atomicAdd(&cnt[cur], (float)count);
    }
}

__global__ __launch_bounds__(512) void final_linear(
        const float* __restrict__ pooled, const float* __restrict__ cnt,
        const float* __restrict__ Wl, const float* __restrict__ bl,
        float* __restrict__ out) {
    int t = threadIdx.x;            // 512 = 256 graphs x 2 classes
    int b = t >> 1, c = t & 1;
    float inv = 1.0f / fmaxf(cnt[b], 1.0f);
    float acc = 0.0f;
#pragma unroll
    for (int fi = 0; fi < 64; ++fi)
        acc += pooled[b * 64 + fi] * Wl[fi * 2 + c];
    out[t] = acc * inv + bl[c];
}

// ---------------------------------------------------------------------------
static inline size_t align256(size_t x) { return (x + 255) & ~size_t(255); }

extern "C" void kernel_launch(void* const* d_in, const int* in_sizes, int n_in,
                              void* d_out, int out_size, void* d_ws, size_t ws_size,
                              hipStream_t stream) {
    const float* x   = (const float*)d_in[0];
    const int*  eraw = (const int*)d_in[1];
    const int*  braw = (const int*)d_in[2];
    const float* W1 = (const float*)d_in[3];
    const float* b1 = (const float*)d_in[4];
    const float* W2 = (const float*)d_in[5];
    const float* b2 = (const float*)d_in[6];
    const float* W3 = (const float*)d_in[7];
    const float* b3 = (const float*)d_in[8];
    const float* Wl = (const float*)d_in[9];
    const float* bl = (const float*)d_in[10];
    float* out = (float*)d_out;

    char* ws = (char*)d_ws;
    size_t off = 0;
    int*   flag   = (int*)(ws + off);   off = align256(off + 256);
    // contiguous zero region: degi, fillc, pooled, cnt
    size_t zoff = off;
    int*   degi   = (int*)(ws + off);   off = align256(off + (size_t)NN * 4);
    int*   fillc  = (int*)(ws + off);   off = align256(off + (size_t)NN * 4);
    float* pooled = (float*)(ws + off); off = align256(off + (size_t)BB * HH * 4);
    float* cnt    = (float*)(ws + off); off = align256(off + (size_t)BB * 4);
    size_t zlen = off - zoff;
    float* dinv   = (float*)(ws + off); off = align256(off + (size_t)NN * 4);
    int*   row    = (int*)(ws + off);   off = align256(off + (size_t)(NN + 1) * 4);
    int*   bsum   = (int*)(ws + off);   off = align256(off + (size_t)NBLK * 4);
    int*   esrc   = (int*)(ws + off);   off = align256(off + (size_t)EE * 4);
    float* bufA   = (float*)(ws + off); off = align256(off + (size_t)NN * HH * 4);
    float* bufB   = (float*)(ws + off); off = align256(off + (size_t)NN * HH * 4);

    const int eBlocks = (EE + 255) / 256;

    detect_i64<<<1, 256, 0, stream>>>(eraw, flag);
    hipMemsetAsync(ws + zoff, 0, zlen, stream);

    // CSR build
    count_kernel<<<eBlocks, 256, 0, stream>>>(eraw, flag, degi);
    scan1<<<NBLK, 256, 0, stream>>>(degi, row, bsum, dinv);
    scan2<<<1, 512, 0, stream>>>(bsum);
    scan3<<<NBLK, 256, 0, stream>>>(row, bsum);
    fill_kernel<<<eBlocks, 256, 0, stream>>>(eraw, flag, row, fillc, esrc);

    // layer 1: g1 = dinv.*(x@W1) -> h1 = relu(conv1)
    gemm_scaled<1><<<GEMM_BLK, 256, 0, stream>>>(x, W1, dinv, bufA);
    gather_chunk<1><<<GATH_BLK, 256, 0, stream>>>(row, esrc, bufA, dinv, b1, bufB);
    // layer 2
    gemm_scaled<0><<<GEMM_BLK, 256, 0, stream>>>(bufB, W2, dinv, bufA);
    gather_chunk<1><<<GATH_BLK, 256, 0, stream>>>(row, esrc, bufA, dinv, b2, bufB);
    // layer 3 (no relu)
    gemm_scaled<0><<<GEMM_BLK, 256, 0, stream>>>(bufB, W3, dinv, bufA);
    gather_chunk<0><<<GATH_BLK, 256, 0, stream>>>(row, esrc, bufA, dinv, b3, bufB);

    // pool + classifier
    pool_kernel<<<NBLK, 256, 0, stream>>>(bufB, braw, flag, pooled, cnt);
    final_linear<<<1, 512, 0, stream>>>(pooled, cnt, Wl, bl, out);
}

// Round 6
// 507.519 us; speedup vs baseline: 1.3933x; 1.3933x over previous
//
#include <hip/hip_runtime.h>

#define NN 100000
#define EE 1250000
#define HH 64
#define BB 256
#define CC 2
#define NBLK 391                       // ceil((NN+1)/256) too (100096 >= 100001)
#define CS ((size_t)(NN + 1) * 8)      // floats per feature-chunk (incl. dummy row NN)
#define NOCT (NN / 8)                  // 12500 node-octets
#define GATH_BLK 8192
#define WPC ((GATH_BLK / 8) * 4)       // waves per chunk = 4096
#define GEMM_BLK 2048
#define GEMM_WAVES (GEMM_BLK * 4)

// ---------------------------------------------------------------------------
// Index dtype detection (int64 vs int32): int64 values < 2^31 -> odd words 0
// ---------------------------------------------------------------------------
__global__ void detect_i64(const int* __restrict__ raw, int* __restrict__ flag) {
    __shared__ int nonzero;
    if (threadIdx.x == 0) nonzero = 0;
    __syncthreads();
    int any = 0;
#pragma unroll
    for (int i = 0; i < 4; ++i) {
        int idx = 2 * (threadIdx.x + i * 256) + 1;
        if (raw[idx] != 0) any = 1;
    }
    if (any) atomicOr(&nonzero, 1);
    __syncthreads();
    if (threadIdx.x == 0) *flag = nonzero ? 0 : 1;   // 1 => int64
}

// ---------------------------------------------------------------------------
// CSR build (padded): per-node segment = [self, edges..., dummy(NN)...] with
// length rounded up to a multiple of 4.
// ---------------------------------------------------------------------------
__global__ void count_kernel(const int* __restrict__ raw, const int* __restrict__ flag,
                             int* __restrict__ degi) {
    int e = blockIdx.x * 256 + threadIdx.x;
    if (e >= EE) return;
    int d = (*flag) ? raw[2 * (EE + e)] : raw[EE + e];
    atomicAdd(&degi[d], 1);
}

// scan over padded degrees pdeg = (deg+1) rounded up to mult of 4; fused dinv
__global__ __launch_bounds__(256) void scan1(const int* __restrict__ degi,
                                             int* __restrict__ row2,
                                             int* __restrict__ bsum,
                                             float* __restrict__ dinv) {
    __shared__ int s[256];
    int tid = threadIdx.x;
    int n = blockIdx.x * 256 + tid;
    int dg = (n < NN) ? degi[n] : 0;
    int v = (n < NN) ? ((dg + 4) & ~3) : 0;   // pdeg
    int x = v;
    s[tid] = x;
    __syncthreads();
    for (int off = 1; off < 256; off <<= 1) {
        int t = (tid >= off) ? s[tid - off] : 0;
        __syncthreads();
        x += t;
        s[tid] = x;
        __syncthreads();
    }
    if (n <= NN) row2[n] = x - v;            // exclusive (partial)
    if (n < NN) dinv[n] = rsqrtf((float)dg + 1.0f);
    if (tid == 255) bsum[blockIdx.x] = x;
}

__global__ __launch_bounds__(512) void scan2(int* __restrict__ bsum) {
    __shared__ int s[512];
    int tid = threadIdx.x;
    int v = (tid < NBLK) ? bsum[tid] : 0;
    int x = v;
    s[tid] = x;
    __syncthreads();
    for (int off = 1; off < 512; off <<= 1) {
        int t = (tid >= off) ? s[tid - off] : 0;
        __syncthreads();
        x += t;
        s[tid] = x;
        __syncthreads();
    }
    if (tid < NBLK) bsum[tid] = x - v;
}

__global__ void scan3(int* __restrict__ row2, const int* __restrict__ bsum) {
    int n = blockIdx.x * 256 + threadIdx.x;
    if (n <= NN) row2[n] += bsum[blockIdx.x];
}

// init padded segments: slot0 = self edge, rest = dummy (row NN)
__global__ void prefill_kernel(const int* __restrict__ row2, int* __restrict__ esrc2) {
    int n = blockIdx.x * 256 + threadIdx.x;
    if (n >= NN) return;
    int b = row2[n], e = row2[n + 1];
    esrc2[b] = n;
    for (int k = b + 1; k < e; ++k) esrc2[k] = NN;
}

// counting sort of real edges into slots [row2[d]+1, ...]
__global__ void fill_kernel(const int* __restrict__ raw, const int* __restrict__ flag,
                            const int* __restrict__ row2, int* __restrict__ fillc,
                            int* __restrict__ esrc2) {
    int e = blockIdx.x * 256 + threadIdx.x;
    if (e >= EE) return;
    int flg = *flag;
    int s = flg ? raw[2 * e]        : raw[e];
    int d = flg ? raw[2 * (EE + e)] : raw[EE + e];
    int pos = row2[d] + 1 + atomicAdd(&fillc[d], 1);
    esrc2[pos] = s;
}

// ---------------------------------------------------------------------------
// G = dinv .* (X @ W), chunk-major out [8][NN+1][8]; row NN zeroed.
// One wave per row. X row read via uniform (scalar) loads; W cols in VGPRs.
// IN_ROW=1: X row-major [NN][64]; IN_ROW=0: X chunk-major.
// ---------------------------------------------------------------------------
template <int IN_ROW>
__global__ __launch_bounds__(256) void gemm_scaled(
        const float* __restrict__ X, const float* __restrict__ W,
        const float* __restrict__ dinv, float* __restrict__ G) {
    int lane = threadIdx.x & 63;
    int gw = (blockIdx.x * 256 + threadIdx.x) >> 6;
    float Wreg[64];
#pragma unroll
    for (int k = 0; k < 64; ++k) Wreg[k] = W[k * 64 + lane];
    int c = lane >> 3, fl = lane & 7;
    for (int n = gw; n <= NN; n += GEMM_WAVES) {
        int nu = __builtin_amdgcn_readfirstlane(n);
        float r = 0.0f;
        if (nu < NN) {
            float a0 = 0.f, a1 = 0.f;
#pragma unroll
            for (int k = 0; k < 64; k += 2) {
                float x0, x1;
                if constexpr (IN_ROW) {
                    x0 = X[(size_t)nu * 64 + k];
                    x1 = X[(size_t)nu * 64 + k + 1];
                } else {
                    x0 = X[(size_t)(k >> 3) * CS + (size_t)nu * 8 + (k & 7)];
                    x1 = X[(size_t)((k + 1) >> 3) * CS + (size_t)nu * 8 + ((k + 1) & 7)];
                }
                a0 = fmaf(x0, Wreg[k], a0);
                a1 = fmaf(x1, Wreg[k + 1], a1);
            }
            r = (a0 + a1) * dinv[nu];
        }
        G[(size_t)c * CS + (size_t)nu * 8 + fl] = r;
    }
}

// ---------------------------------------------------------------------------
// XCD-sharded gather, 8 nodes per wave (lane = node_sub(8) x feat(8)).
// Each lane owns (node, feat): no cross-lane reduce. Padded CSR: no bounds
// checks; self edge included; dummies read zeroed row NN.
// out = dinv_n * sum_slots G[s] + bias  [; relu]
// ---------------------------------------------------------------------------
template <int RELU>
__global__ __launch_bounds__(256) void gather8(
        const int* __restrict__ row2, const int* __restrict__ esrc2,
        const float* __restrict__ G, const float* __restrict__ dinv,
        const float* __restrict__ bias, float* __restrict__ Out) {
    int lane = threadIdx.x & 63;
    int fl = lane & 7, g = lane >> 3;
    int chunk = blockIdx.x & 7;
    int wv = ((blockIdx.x >> 3) << 2) + (threadIdx.x >> 6);
    const float* __restrict__ Gc = G + (size_t)chunk * CS;
    float bv = bias[chunk * 8 + fl];

    for (int oct = wv; oct < NOCT; oct += WPC) {
        int n = oct * 8 + g;
        int beg = row2[n], end = row2[n + 1];
        float a0 = 0.f, a1 = 0.f;
        for (int j = beg; j < end; j += 4) {
            int4 mm = *reinterpret_cast<const int4*>(esrc2 + j);
            float g0 = Gc[(size_t)mm.x * 8 + fl];
            float g1 = Gc[(size_t)mm.y * 8 + fl];
            float g2 = Gc[(size_t)mm.z * 8 + fl];
            float g3 = Gc[(size_t)mm.w * 8 + fl];
            a0 += g0 + g2;
            a1 += g1 + g3;
        }
        float o = fmaf(a0 + a1, dinv[n], bv);
        if constexpr (RELU) o = fmaxf(o, 0.f);
        Out[(size_t)chunk * CS + (size_t)oct * 64 + lane] = o;  // 256B coalesced
    }
}

// ---------------------------------------------------------------------------
// Mean pool (batch sorted, chunk-major input) + final linear
// ---------------------------------------------------------------------------
__global__ __launch_bounds__(256) void pool_kernel(
        const float* __restrict__ Hc, const int* __restrict__ braw,
        const int* __restrict__ flag,
        float* __restrict__ pooled, float* __restrict__ cnt) {
    int tid = threadIdx.x;
    int f = tid & 63, sub = tid >> 6;
    int c = f >> 3, fl = f & 7;
    int flg = *flag;
    int base = blockIdx.x * 256 + sub * 64;
    float acc = 0.0f;
    int cur = -1, count = 0;
    for (int i = 0; i < 64; ++i) {
        int n = base + i;
        if (n >= NN) break;
        int g = flg ? braw[2 * n] : braw[n];
        if (g != cur) {
            if (cur >= 0) {
                atomicAdd(&pooled[cur * 64 + f], acc);
                if (f == 0) atomicAdd(&cnt[cur], (float)count);
            }
            cur = g; acc = 0.0f; count = 0;
        }
        acc += Hc[(size_t)c * CS + (size_t)n * 8 + fl];
        ++count;
    }
    if (cur >= 0) {
        atomicAdd(&pooled[cur * 64 + f], acc);
        if (f == 0) atomicAdd(&cnt[cur], (float)count);
    }
}

__global__ __launch_bounds__(512) void final_linear(
        const float* __restrict__ pooled, const float* __restrict__ cnt,
        const float* __restrict__ Wl, const float* __restrict__ bl,
        float* __restrict__ out) {
    int t = threadIdx.x;            // 512 = 256 graphs x 2 classes
    int b = t >> 1, c = t & 1;
    float inv = 1.0f / fmaxf(cnt[b], 1.0f);
    float acc = 0.0f;
#pragma unroll
    for (int fi = 0; fi < 64; ++fi)
        acc += pooled[b * 64 + fi] * Wl[fi * 2 + c];
    out[t] = acc * inv + bl[c];
}

// ---------------------------------------------------------------------------
static inline size_t align256(size_t x) { return (x + 255) & ~size_t(255); }

extern "C" void kernel_launch(void* const* d_in, const int* in_sizes, int n_in,
                              void* d_out, int out_size, void* d_ws, size_t ws_size,
                              hipStream_t stream) {
    const float* x   = (const float*)d_in[0];
    const int*  eraw = (const int*)d_in[1];
    const int*  braw = (const int*)d_in[2];
    const float* W1 = (const float*)d_in[3];
    const float* b1 = (const float*)d_in[4];
    const float* W2 = (const float*)d_in[5];
    const float* b2 = (const float*)d_in[6];
    const float* W3 = (const float*)d_in[7];
    const float* b3 = (const float*)d_in[8];
    const float* Wl = (const float*)d_in[9];
    const float* bl = (const float*)d_in[10];
    float* out = (float*)d_out;

    char* ws = (char*)d_ws;
    size_t off = 0;
    int*   flag   = (int*)(ws + off);   off = align256(off + 256);
    // contiguous zero region: degi, fillc, pooled, cnt
    size_t zoff = off;
    int*   degi   = (int*)(ws + off);   off = align256(off + (size_t)NN * 4);
    int*   fillc  = (int*)(ws + off);   off = align256(off + (size_t)NN * 4);
    float* pooled = (float*)(ws + off); off = align256(off + (size_t)BB * HH * 4);
    float* cnt    = (float*)(ws + off); off = align256(off + (size_t)BB * 4);
    size_t zlen = off - zoff;
    float* dinv   = (float*)(ws + off); off = align256(off + (size_t)(NN + 1) * 4);
    int*   row2   = (int*)(ws + off);   off = align256(off + (size_t)(NN + 1) * 4);
    int*   bsum   = (int*)(ws + off);   off = align256(off + (size_t)NBLK * 4);
    int*   esrc2  = (int*)(ws + off);   off = align256(off + ((size_t)EE + 4 * NN + 64) * 4);
    float* bufA   = (float*)(ws + off); off = align256(off + (size_t)8 * CS * 4);
    float* bufB   = (float*)(ws + off); off = align256(off + (size_t)8 * CS * 4);

    const int eBlocks = (EE + 255) / 256;

    detect_i64<<<1, 256, 0, stream>>>(eraw, flag);
    hipMemsetAsync(ws + zoff, 0, zlen, stream);

    // padded CSR build
    count_kernel<<<eBlocks, 256, 0, stream>>>(eraw, flag, degi);
    scan1<<<NBLK, 256, 0, stream>>>(degi, row2, bsum, dinv);
    scan2<<<1, 512, 0, stream>>>(bsum);
    scan3<<<NBLK, 256, 0, stream>>>(row2, bsum);
    prefill_kernel<<<NBLK, 256, 0, stream>>>(row2, esrc2);
    fill_kernel<<<eBlocks, 256, 0, stream>>>(eraw, flag, row2, fillc, esrc2);

    // layer 1
    gemm_scaled<1><<<GEMM_BLK, 256, 0, stream>>>(x, W1, dinv, bufA);
    gather8<1><<<GATH_BLK, 256, 0, stream>>>(row2, esrc2, bufA, dinv, b1, bufB);
    // layer 2
    gemm_scaled<0><<<GEMM_BLK, 256, 0, stream>>>(bufB, W2, dinv, bufA);
    gather8<1><<<GATH_BLK, 256, 0, stream>>>(row2, esrc2, bufA, dinv, b2, bufB);
    // layer 3 (no relu)
    gemm_scaled<0><<<GEMM_BLK, 256, 0, stream>>>(bufB, W3, dinv, bufA);
    gather8<0><<<GATH_BLK, 256, 0, stream>>>(row2, esrc2, bufA, dinv, b3, bufB);

    // pool + classifier
    pool_kernel<<<NBLK, 256, 0, stream>>>(bufB, braw, flag, pooled, cnt);
    final_linear<<<1, 512, 0, stream>>>(pooled, cnt, Wl, bl, out);
}

// Round 8
// 494.715 us; speedup vs baseline: 1.4293x; 1.0259x over previous
//
#include <hip/hip_runtime.h>

#define NN 100000
#define EE 1250000
#define HH 64
#define BB 256
#define CC 2
#define NBLK 391                       // ceil((NN+1)/256)
#define CS ((size_t)(NN + 1) * 8)      // floats per feature-chunk (incl. dummy row NN)
#define NOCT (NN / 8)                  // 12500 node-octets
#define GATH_BLK 8192
#define WPC ((GATH_BLK / 8) * 4)       // waves per chunk = 4096
#define GEMM_BLK 2048
#define GEMM_WAVES (GEMM_BLK * 4)
#define NSH 12500                      // nodes per XCD shard (NN/8)
#define FS_PER 96                      // fill blocks per shard
#define PRE_PER 49                     // prefill blocks per shard (49*256 >= 12500)

typedef int ivec4 __attribute__((ext_vector_type(4)));

// ---------------------------------------------------------------------------
// Index dtype detection (int64 vs int32): int64 values < 2^31 -> odd words 0
// ---------------------------------------------------------------------------
__global__ void detect_i64(const int* __restrict__ raw, int* __restrict__ flag) {
    __shared__ int nonzero;
    if (threadIdx.x == 0) nonzero = 0;
    __syncthreads();
    int any = 0;
#pragma unroll
    for (int i = 0; i < 4; ++i) {
        int idx = 2 * (threadIdx.x + i * 256) + 1;
        if (raw[idx] != 0) any = 1;
    }
    if (any) atomicOr(&nonzero, 1);
    __syncthreads();
    if (threadIdx.x == 0) *flag = nonzero ? 0 : 1;   // 1 => int64
}

// ---------------------------------------------------------------------------
// count + convert: degree count, and densify indices to int32 (nt stores)
// ---------------------------------------------------------------------------
__global__ void count_conv(const int* __restrict__ raw, const int* __restrict__ flag,
                           int* __restrict__ degi,
                           int* __restrict__ src32, int* __restrict__ dst32) {
    int e = blockIdx.x * 256 + threadIdx.x;
    if (e >= EE) return;
    int flg = *flag;
    int s = flg ? raw[2 * e]        : raw[e];
    int d = flg ? raw[2 * (EE + e)] : raw[EE + e];
    __builtin_nontemporal_store(s, src32 + e);
    __builtin_nontemporal_store(d, dst32 + e);
    atomicAdd(&degi[d], 1);
}

// scan over padded degrees pdeg = (deg+1) rounded up to mult of 4; fused dinv
__global__ __launch_bounds__(256) void scan1(const int* __restrict__ degi,
                                             int* __restrict__ row2,
                                             int* __restrict__ bsum,
                                             float* __restrict__ dinv) {
    __shared__ int s[256];
    int tid = threadIdx.x;
    int n = blockIdx.x * 256 + tid;
    int dg = (n < NN) ? degi[n] : 0;
    int v = (n < NN) ? ((dg + 4) & ~3) : 0;   // pdeg
    int x = v;
    s[tid] = x;
    __syncthreads();
    for (int off = 1; off < 256; off <<= 1) {
        int t = (tid >= off) ? s[tid - off] : 0;
        __syncthreads();
        x += t;
        s[tid] = x;
        __syncthreads();
    }
    if (n <= NN) row2[n] = x - v;            // exclusive (partial)
    if (n < NN) dinv[n] = rsqrtf((float)dg + 1.0f);
    if (tid == 255) bsum[blockIdx.x] = x;
}

__global__ __launch_bounds__(512) void scan2(int* __restrict__ bsum) {
    __shared__ int s[512];
    int tid = threadIdx.x;
    int v = (tid < NBLK) ? bsum[tid] : 0;
    int x = v;
    s[tid] = x;
    __syncthreads();
    for (int off = 1; off < 512; off <<= 1) {
        int t = (tid >= off) ? s[tid - off] : 0;
        __syncthreads();
        x += t;
        s[tid] = x;
        __syncthreads();
    }
    if (tid < NBLK) bsum[tid] = x - v;
}

__global__ void scan3(int* __restrict__ row2, const int* __restrict__ bsum) {
    int n = blockIdx.x * 256 + threadIdx.x;
    if (n <= NN) row2[n] += bsum[blockIdx.x];
}

// ---------------------------------------------------------------------------
// XCD-sharded prefill: write ONLY the self-slot and the padding tail
// (slots the fill pass won't touch). shard = blockIdx&7 -> node range.
// ---------------------------------------------------------------------------
__global__ void prefill_shard(const int* __restrict__ row2, const int* __restrict__ degi,
                              int* __restrict__ esrc2) {
    int shard = blockIdx.x & 7;
    int lb = blockIdx.x >> 3;
    int ln = lb * 256 + threadIdx.x;
    if (ln >= NSH) return;
    int n = shard * NSH + ln;
    int b = row2[n], e = row2[n + 1], dg = degi[n];
    esrc2[b] = n;                                  // self edge
    for (int k = b + 1 + dg; k < e; ++k) esrc2[k] = NN;  // padding -> zero row
}

// ---------------------------------------------------------------------------
// XCD-sharded counting-sort fill: shard owns dst range [lo,hi); its esrc2
// window (~660KB) stays L2-resident so scattered 4B writes merge per line.
// dst stream read nontemporal (ivec4) to avoid evicting the write window.
// ---------------------------------------------------------------------------
__global__ __launch_bounds__(256) void fill_shard(
        const int* __restrict__ src32, const int* __restrict__ dst32,
        const int* __restrict__ row2, int* __restrict__ fillc,
        int* __restrict__ esrc2) {
    int shard = blockIdx.x & 7;
    int lb = blockIdx.x >> 3;
    int lo = shard * NSH, hi = lo + NSH;
    const ivec4* __restrict__ dst4 = reinterpret_cast<const ivec4*>(dst32);
    for (int q = lb * 256 + threadIdx.x; q < EE / 4; q += FS_PER * 256) {
        ivec4 d4 = __builtin_nontemporal_load(dst4 + q);
        int e = q * 4;
#pragma unroll
        for (int k = 0; k < 4; ++k) {
            int d = d4[k];
            if (d >= lo && d < hi) {
                int s = __builtin_nontemporal_load(src32 + e + k);
                int pos = row2[d] + 1 + atomicAdd(&fillc[d], 1);
                esrc2[pos] = s;
            }
        }
    }
}

// ---------------------------------------------------------------------------
// G = dinv .* (X @ W), chunk-major out [8][NN+1][8]; row NN zeroed.
// One wave per row. X row read via uniform (scalar) loads; W cols in VGPRs.
// ---------------------------------------------------------------------------
template <int IN_ROW>
__global__ __launch_bounds__(256) void gemm_scaled(
        const float* __restrict__ X, const float* __restrict__ W,
        const float* __restrict__ dinv, float* __restrict__ G) {
    int lane = threadIdx.x & 63;
    int gw = (blockIdx.x * 256 + threadIdx.x) >> 6;
    float Wreg[64];
#pragma unroll
    for (int k = 0; k < 64; ++k) Wreg[k] = W[k * 64 + lane];
    int c = lane >> 3, fl = lane & 7;
    for (int n = gw; n <= NN; n += GEMM_WAVES) {
        int nu = __builtin_amdgcn_readfirstlane(n);
        float r = 0.0f;
        if (nu < NN) {
            float a0 = 0.f, a1 = 0.f;
#pragma unroll
            for (int k = 0; k < 64; k += 2) {
                float x0, x1;
                if constexpr (IN_ROW) {
                    x0 = X[(size_t)nu * 64 + k];
                    x1 = X[(size_t)nu * 64 + k + 1];
                } else {
                    x0 = X[(size_t)(k >> 3) * CS + (size_t)nu * 8 + (k & 7)];
                    x1 = X[(size_t)((k + 1) >> 3) * CS + (size_t)nu * 8 + ((k + 1) & 7)];
                }
                a0 = fmaf(x0, Wreg[k], a0);
                a1 = fmaf(x1, Wreg[k + 1], a1);
            }
            r = (a0 + a1) * dinv[nu];
        }
        G[(size_t)c * CS + (size_t)nu * 8 + fl] = r;
    }
}

// ---------------------------------------------------------------------------
// XCD-sharded gather, 8 nodes per wave (lane = node_sub(8) x feat(8)).
// ---------------------------------------------------------------------------
template <int RELU>
__global__ __launch_bounds__(256) void gather8(
        const int* __restrict__ row2, const int* __restrict__ esrc2,
        const float* __restrict__ G, const float* __restrict__ dinv,
        const float* __restrict__ bias, float* __restrict__ Out) {
    int lane = threadIdx.x & 63;
    int fl = lane & 7, g = lane >> 3;
    int chunk = blockIdx.x & 7;
    int wv = ((blockIdx.x >> 3) << 2) + (threadIdx.x >> 6);
    const float* __restrict__ Gc = G + (size_t)chunk * CS;
    float bv = bias[chunk * 8 + fl];

    for (int oct = wv; oct < NOCT; oct += WPC) {
        int n = oct * 8 + g;
        int beg = row2[n], end = row2[n + 1];
        float a0 = 0.f, a1 = 0.f;
        for (int j = beg; j < end; j += 4) {
            const int* p = esrc2 + j;
            int m0 = p[0], m1 = p[1], m2 = p[2], m3 = p[3];
            float g0 = Gc[(size_t)m0 * 8 + fl];
            float g1 = Gc[(size_t)m1 * 8 + fl];
            float g2 = Gc[(size_t)m2 * 8 + fl];
            float g3 = Gc[(size_t)m3 * 8 + fl];
            a0 += g0 + g2;
            a1 += g1 + g3;
        }
        float o = fmaf(a0 + a1, dinv[n], bv);
        if constexpr (RELU) o = fmaxf(o, 0.f);
        Out[(size_t)chunk * CS + (size_t)oct * 64 + lane] = o;  // 256B coalesced
    }
}

// ---------------------------------------------------------------------------
// Mean pool (batch sorted, chunk-major input) + final linear
// ---------------------------------------------------------------------------
__global__ __launch_bounds__(256) void pool_kernel(
        const float* __restrict__ Hc, const int* __restrict__ braw,
        const int* __restrict__ flag,
        float* __restrict__ pooled, float* __restrict__ cnt) {
    int tid = threadIdx.x;
    int f = tid & 63, sub = tid >> 6;
    int c = f >> 3, fl = f & 7;
    int flg = *flag;
    int base = blockIdx.x * 256 + sub * 64;
    float acc = 0.0f;
    int cur = -1, count = 0;
    for (int i = 0; i < 64; ++i) {
        int n = base + i;
        if (n >= NN) break;
        int g = flg ? braw[2 * n] : braw[n];
        if (g != cur) {
            if (cur >= 0) {
                atomicAdd(&pooled[cur * 64 + f], acc);
                if (f == 0) atomicAdd(&cnt[cur], (float)count);
            }
            cur = g; acc = 0.0f; count = 0;
        }
        acc += Hc[(size_t)c * CS + (size_t)n * 8 + fl];
        ++count;
    }
    if (cur >= 0) {
        atomicAdd(&pooled[cur * 64 + f], acc);
        if (f == 0) atomicAdd(&cnt[cur], (float)count);
    }
}

__global__ __launch_bounds__(512) void final_linear(
        const float* __restrict__ pooled, const float* __restrict__ cnt,
        const float* __restrict__ Wl, const float* __restrict__ bl,
        float* __restrict__ out) {
    int t = threadIdx.x;            // 512 = 256 graphs x 2 classes
    int b = t >> 1, c = t & 1;
    float inv = 1.0f / fmaxf(cnt[b], 1.0f);
    float acc = 0.0f;
#pragma unroll
    for (int fi = 0; fi < 64; ++fi)
        acc += pooled[b * 64 + fi] * Wl[fi * 2 + c];
    out[t] = acc * inv + bl[c];
}

// ---------------------------------------------------------------------------
static inline size_t align256(size_t x) { return (x + 255) & ~size_t(255); }

extern "C" void kernel_launch(void* const* d_in, const int* in_sizes, int n_in,
                              void* d_out, int out_size, void* d_ws, size_t ws_size,
                              hipStream_t stream) {
    const float* x   = (const float*)d_in[0];
    const int*  eraw = (const int*)d_in[1];
    const int*  braw = (const int*)d_in[2];
    const float* W1 = (const float*)d_in[3];
    const float* b1 = (const float*)d_in[4];
    const float* W2 = (const float*)d_in[5];
    const float* b2 = (const float*)d_in[6];
    const float* W3 = (const float*)d_in[7];
    const float* b3 = (const float*)d_in[8];
    const float* Wl = (const float*)d_in[9];
    const float* bl = (const float*)d_in[10];
    float* out = (float*)d_out;

    char* ws = (char*)d_ws;
    size_t off = 0;
    int*   flag   = (int*)(ws + off);   off = align256(off + 256);
    // contiguous zero region: degi, fillc, pooled, cnt
    size_t zoff = off;
    int*   degi   = (int*)(ws + off);   off = align256(off + (size_t)NN * 4);
    int*   fillc  = (int*)(ws + off);   off = align256(off + (size_t)NN * 4);
    float* pooled = (float*)(ws + off); off = align256(off + (size_t)BB * HH * 4);
    float* cnt    = (float*)(ws + off); off = align256(off + (size_t)BB * 4);
    size_t zlen = off - zoff;
    float* dinv   = (float*)(ws + off); off = align256(off + (size_t)(NN + 1) * 4);
    int*   row2   = (int*)(ws + off);   off = align256(off + (size_t)(NN + 1) * 4);
    int*   bsum   = (int*)(ws + off);   off = align256(off + (size_t)NBLK * 4);
    int*   src32  = (int*)(ws + off);   off = align256(off + (size_t)EE * 4);
    int*   dst32  = (int*)(ws + off);   off = align256(off + (size_t)EE * 4);
    int*   esrc2  = (int*)(ws + off);   off = align256(off + ((size_t)EE + 4 * NN + 64) * 4);
    float* bufA   = (float*)(ws + off); off = align256(off + (size_t)8 * CS * 4);
    float* bufB   = (float*)(ws + off); off = align256(off + (size_t)8 * CS * 4);

    const int eBlocks = (EE + 255) / 256;

    detect_i64<<<1, 256, 0, stream>>>(eraw, flag);
    (void)hipMemsetAsync(ws + zoff, 0, zlen, stream);

    // padded CSR build (XCD-sharded fill)
    count_conv<<<eBlocks, 256, 0, stream>>>(eraw, flag, degi, src32, dst32);
    scan1<<<NBLK, 256, 0, stream>>>(degi, row2, bsum, dinv);
    scan2<<<1, 512, 0, stream>>>(bsum);
    scan3<<<NBLK, 256, 0, stream>>>(row2, bsum);
    prefill_shard<<<8 * PRE_PER, 256, 0, stream>>>(row2, degi, esrc2);
    fill_shard<<<8 * FS_PER, 256, 0, stream>>>(src32, dst32, row2, fillc, esrc2);

    // layer 1
    gemm_scaled<1><<<GEMM_BLK, 256, 0, stream>>>(x, W1, dinv, bufA);
    gather8<1><<<GATH_BLK, 256, 0, stream>>>(row2, esrc2, bufA, dinv, b1, bufB);
    // layer 2
    gemm_scaled<0><<<GEMM_BLK, 256, 0, stream>>>(bufB, W2, dinv, bufA);
    gather8<1><<<GATH_BLK, 256, 0, stream>>>(row2, esrc2, bufA, dinv, b2, bufB);
    // layer 3 (no relu)
    gemm_scaled<0><<<GEMM_BLK, 256, 0, stream>>>(bufB, W3, dinv, bufA);
    gather8<0><<<GATH_BLK, 256, 0, stream>>>(row2, esrc2, bufA, dinv, b3, bufB);

    // pool + classifier
    pool_kernel<<<NBLK, 256, 0, stream>>>(bufB, braw, flag, pooled, cnt);
    final_linear<<<1, 512, 0, stream>>>(pooled, cnt, Wl, bl, out);
}

// Round 9
// 476.569 us; speedup vs baseline: 1.4838x; 1.0381x over previous
//
#include <hip/hip_runtime.h>

#define NN 100000
#define EE 1250000
#define HH 64
#define BB 256
#define CC 2
#define NBLK 391                       // ceil((NN+1)/256)
#define CS ((size_t)(NN + 1) * 8)      // floats per feature-chunk (incl. dummy row NN)
#define NOCT (NN / 8)                  // 12500 node-octets
#define GATH_BLK 8192
#define WPC ((GATH_BLK / 8) * 4)       // waves per chunk = 4096
#define GEMM_BLK 2048
#define GEMM_WAVES (GEMM_BLK * 4)
#define NSH 12500                      // nodes per XCD shard (NN/8)
#define CAP 170000                     // bucket capacity (expect 156250, sigma~370)
#define FSB_PER 128                    // fill blocks per shard
#define PRE_PER 49                     // prefill blocks per shard (49*256 >= 12500)
#define CB_BLK ((EE + 1023) / 1024)    // count_bucket blocks (1024 edges each)

typedef int ivec4 __attribute__((ext_vector_type(4)));
typedef int ivec2 __attribute__((ext_vector_type(2)));

// ---------------------------------------------------------------------------
// Index dtype detection (int64 vs int32): int64 values < 2^31 -> odd words 0
// ---------------------------------------------------------------------------
__global__ void detect_i64(const int* __restrict__ raw, int* __restrict__ flag) {
    __shared__ int nonzero;
    if (threadIdx.x == 0) nonzero = 0;
    __syncthreads();
    int any = 0;
#pragma unroll
    for (int i = 0; i < 4; ++i) {
        int idx = 2 * (threadIdx.x + i * 256) + 1;
        if (raw[idx] != 0) any = 1;
    }
    if (any) atomicOr(&nonzero, 1);
    __syncthreads();
    if (threadIdx.x == 0) *flag = nonzero ? 0 : 1;   // 1 => int64
}

// ---------------------------------------------------------------------------
// Pass A: degree count + bucketize edges by dst-shard (8 buckets).
// Per-block LDS histogram -> one global atomicAdd per bucket -> coalesced
// segment writes of (src,dst) pairs into fixed-capacity buckets.
// ---------------------------------------------------------------------------
__global__ __launch_bounds__(256) void count_bucket(
        const int* __restrict__ raw, const int* __restrict__ flag,
        int* __restrict__ degi, int* __restrict__ bfill,
        ivec2* __restrict__ pairs) {
    __shared__ int lh[8];
    __shared__ int lbase[8];
    int tid = threadIdx.x;
    if (tid < 8) lh[tid] = 0;
    __syncthreads();
    int flg = *flag;
    int e0 = blockIdx.x * 1024 + tid;
    int sv[4], dv[4], rk[4], bk[4];
#pragma unroll
    for (int i = 0; i < 4; ++i) {
        int e = e0 + i * 256;
        if (e < EE) {
            int s = flg ? raw[2 * e]        : raw[e];
            int d = flg ? raw[2 * (EE + e)] : raw[EE + e];
            atomicAdd(&degi[d], 1);
            int b = d / NSH;               // const divide -> magic mul
            bk[i] = b;
            rk[i] = atomicAdd(&lh[b], 1);  // local rank (LDS atomic)
            sv[i] = s; dv[i] = d;
        } else {
            bk[i] = -1; sv[i] = 0; dv[i] = 0; rk[i] = 0;
        }
    }
    __syncthreads();
    if (tid < 8) lbase[tid] = atomicAdd(&bfill[tid], lh[tid]);
    __syncthreads();
#pragma unroll
    for (int i = 0; i < 4; ++i) {
        if (bk[i] >= 0) {
            int pos = bk[i] * CAP + lbase[bk[i]] + rk[i];
            ivec2 pr; pr.x = sv[i]; pr.y = dv[i];
            pairs[pos] = pr;
        }
    }
}

// scan over padded degrees pdeg = (deg+1) rounded up to mult of 4; fused dinv
__global__ __launch_bounds__(256) void scan1(const int* __restrict__ degi,
                                             int* __restrict__ row2,
                                             int* __restrict__ bsum,
                                             float* __restrict__ dinv) {
    __shared__ int s[256];
    int tid = threadIdx.x;
    int n = blockIdx.x * 256 + tid;
    int dg = (n < NN) ? degi[n] : 0;
    int v = (n < NN) ? ((dg + 4) & ~3) : 0;   // pdeg
    int x = v;
    s[tid] = x;
    __syncthreads();
    for (int off = 1; off < 256; off <<= 1) {
        int t = (tid >= off) ? s[tid - off] : 0;
        __syncthreads();
        x += t;
        s[tid] = x;
        __syncthreads();
    }
    if (n <= NN) row2[n] = x - v;            // exclusive (partial)
    if (n < NN) dinv[n] = rsqrtf((float)dg + 1.0f);
    if (tid == 255) bsum[blockIdx.x] = x;
}

__global__ __launch_bounds__(512) void scan2(int* __restrict__ bsum) {
    __shared__ int s[512];
    int tid = threadIdx.x;
    int v = (tid < NBLK) ? bsum[tid] : 0;
    int x = v;
    s[tid] = x;
    __syncthreads();
    for (int off = 1; off < 512; off <<= 1) {
        int t = (tid >= off) ? s[tid - off] : 0;
        __syncthreads();
        x += t;
        s[tid] = x;
        __syncthreads();
    }
    if (tid < NBLK) bsum[tid] = x - v;
}

__global__ void scan3(int* __restrict__ row2, const int* __restrict__ bsum) {
    int n = blockIdx.x * 256 + threadIdx.x;
    if (n <= NN) row2[n] += bsum[blockIdx.x];
}

// ---------------------------------------------------------------------------
// XCD-sharded prefill: write ONLY the self-slot and the padding tail
// ---------------------------------------------------------------------------
__global__ void prefill_shard(const int* __restrict__ row2, const int* __restrict__ degi,
                              int* __restrict__ esrc2) {
    int shard = blockIdx.x & 7;
    int lb = blockIdx.x >> 3;
    int ln = lb * 256 + threadIdx.x;
    if (ln >= NSH) return;
    int n = shard * NSH + ln;
    int b = row2[n], e = row2[n + 1], dg = degi[n];
    esrc2[b] = n;                                  // self edge
    for (int k = b + 1 + dg; k < e; ++k) esrc2[k] = NN;  // padding -> zero row
}

// ---------------------------------------------------------------------------
// Pass B: per-shard counting-sort fill. Shard s (XCD s) reads ONLY its own
// bucket (1.36MB sequential); writes stay in its ~825KB esrc2 window.
// Total resident ~2.3MB < 4MB L2 -> dirty lines merge fully.
// ---------------------------------------------------------------------------
__global__ __launch_bounds__(256) void fill_shard2(
        const ivec2* __restrict__ pairs, const int* __restrict__ bfill,
        const int* __restrict__ row2, int* __restrict__ fillc,
        int* __restrict__ esrc2) {
    int shard = blockIdx.x & 7;
    int lb = blockIdx.x >> 3;
    int tot = bfill[shard];
    const ivec2* __restrict__ bp = pairs + (size_t)shard * CAP;
    for (int i = lb * 256 + threadIdx.x; i < tot; i += FSB_PER * 256) {
        ivec2 p = bp[i];
        int pos = row2[p.y] + 1 + atomicAdd(&fillc[p.y], 1);
        esrc2[pos] = p.x;
    }
}

// ---------------------------------------------------------------------------
// G = dinv .* (X @ W), chunk-major out [8][NN+1][8]; row NN zeroed.
// ---------------------------------------------------------------------------
template <int IN_ROW>
__global__ __launch_bounds__(256) void gemm_scaled(
        const float* __restrict__ X, const float* __restrict__ W,
        const float* __restrict__ dinv, float* __restrict__ G) {
    int lane = threadIdx.x & 63;
    int gw = (blockIdx.x * 256 + threadIdx.x) >> 6;
    float Wreg[64];
#pragma unroll
    for (int k = 0; k < 64; ++k) Wreg[k] = W[k * 64 + lane];
    int c = lane >> 3, fl = lane & 7;
    for (int n = gw; n <= NN; n += GEMM_WAVES) {
        int nu = __builtin_amdgcn_readfirstlane(n);
        float r = 0.0f;
        if (nu < NN) {
            float a0 = 0.f, a1 = 0.f;
#pragma unroll
            for (int k = 0; k < 64; k += 2) {
                float x0, x1;
                if constexpr (IN_ROW) {
                    x0 = X[(size_t)nu * 64 + k];
                    x1 = X[(size_t)nu * 64 + k + 1];
                } else {
                    x0 = X[(size_t)(k >> 3) * CS + (size_t)nu * 8 + (k & 7)];
                    x1 = X[(size_t)((k + 1) >> 3) * CS + (size_t)nu * 8 + ((k + 1) & 7)];
                }
                a0 = fmaf(x0, Wreg[k], a0);
                a1 = fmaf(x1, Wreg[k + 1], a1);
            }
            r = (a0 + a1) * dinv[nu];
        }
        G[(size_t)c * CS + (size_t)nu * 8 + fl] = r;
    }
}

// ---------------------------------------------------------------------------
// XCD-sharded gather, 8 nodes per wave (lane = node_sub(8) x feat(8)).
// ---------------------------------------------------------------------------
template <int RELU>
__global__ __launch_bounds__(256) void gather8(
        const int* __restrict__ row2, const int* __restrict__ esrc2,
        const float* __restrict__ G, const float* __restrict__ dinv,
        const float* __restrict__ bias, float* __restrict__ Out) {
    int lane = threadIdx.x & 63;
    int fl = lane & 7, g = lane >> 3;
    int chunk = blockIdx.x & 7;
    int wv = ((blockIdx.x >> 3) << 2) + (threadIdx.x >> 6);
    const float* __restrict__ Gc = G + (size_t)chunk * CS;
    float bv = bias[chunk * 8 + fl];

    for (int oct = wv; oct < NOCT; oct += WPC) {
        int n = oct * 8 + g;
        int beg = row2[n], end = row2[n + 1];
        float a0 = 0.f, a1 = 0.f;
        for (int j = beg; j < end; j += 4) {
            const int* p = esrc2 + j;
            int m0 = p[0], m1 = p[1], m2 = p[2], m3 = p[3];
            float g0 = Gc[(size_t)m0 * 8 + fl];
            float g1 = Gc[(size_t)m1 * 8 + fl];
            float g2 = Gc[(size_t)m2 * 8 + fl];
            float g3 = Gc[(size_t)m3 * 8 + fl];
            a0 += g0 + g2;
            a1 += g1 + g3;
        }
        float o = fmaf(a0 + a1, dinv[n], bv);
        if constexpr (RELU) o = fmaxf(o, 0.f);
        Out[(size_t)chunk * CS + (size_t)oct * 64 + lane] = o;  // 256B coalesced
    }
}

// ---------------------------------------------------------------------------
// Mean pool (batch sorted, chunk-major input) + final linear
// ---------------------------------------------------------------------------
__global__ __launch_bounds__(256) void pool_kernel(
        const float* __restrict__ Hc, const int* __restrict__ braw,
        const int* __restrict__ flag,
        float* __restrict__ pooled, float* __restrict__ cnt) {
    int tid = threadIdx.x;
    int f = tid & 63, sub = tid >> 6;
    int c = f >> 3, fl = f & 7;
    int flg = *flag;
    int base = blockIdx.x * 256 + sub * 64;
    float acc = 0.0f;
    int cur = -1, count = 0;
    for (int i = 0; i < 64; ++i) {
        int n = base + i;
        if (n >= NN) break;
        int g = flg ? braw[2 * n] : braw[n];
        if (g != cur) {
            if (cur >= 0) {
                atomicAdd(&pooled[cur * 64 + f], acc);
                if (f == 0) atomicAdd(&cnt[cur], (float)count);
            }
            cur = g; acc = 0.0f; count = 0;
        }
        acc += Hc[(size_t)c * CS + (size_t)n * 8 + fl];
        ++count;
    }
    if (cur >= 0) {
        atomicAdd(&pooled[cur * 64 + f], acc);
        if (f == 0) atomicAdd(&cnt[cur], (float)count);
    }
}

__global__ __launch_bounds__(512) void final_linear(
        const float* __restrict__ pooled, const float* __restrict__ cnt,
        const float* __restrict__ Wl, const float* __restrict__ bl,
        float* __restrict__ out) {
    int t = threadIdx.x;            // 512 = 256 graphs x 2 classes
    int b = t >> 1, c = t & 1;
    float inv = 1.0f / fmaxf(cnt[b], 1.0f);
    float acc = 0.0f;
#pragma unroll
    for (int fi = 0; fi < 64; ++fi)
        acc += pooled[b * 64 + fi] * Wl[fi * 2 + c];
    out[t] = acc * inv + bl[c];
}

// ---------------------------------------------------------------------------
static inline size_t align256(size_t x) { return (x + 255) & ~size_t(255); }

extern "C" void kernel_launch(void* const* d_in, const int* in_sizes, int n_in,
                              void* d_out, int out_size, void* d_ws, size_t ws_size,
                              hipStream_t stream) {
    const float* x   = (const float*)d_in[0];
    const int*  eraw = (const int*)d_in[1];
    const int*  braw = (const int*)d_in[2];
    const float* W1 = (const float*)d_in[3];
    const float* b1 = (const float*)d_in[4];
    const float* W2 = (const float*)d_in[5];
    const float* b2 = (const float*)d_in[6];
    const float* W3 = (const float*)d_in[7];
    const float* b3 = (const float*)d_in[8];
    const float* Wl = (const float*)d_in[9];
    const float* bl = (const float*)d_in[10];
    float* out = (float*)d_out;

    char* ws = (char*)d_ws;
    size_t off = 0;
    int*   flag   = (int*)(ws + off);   off = align256(off + 256);
    // contiguous zero region: degi, fillc, bfill, pooled, cnt
    size_t zoff = off;
    int*   degi   = (int*)(ws + off);   off = align256(off + (size_t)NN * 4);
    int*   fillc  = (int*)(ws + off);   off = align256(off + (size_t)NN * 4);
    int*   bfill  = (int*)(ws + off);   off = align256(off + 256);
    float* pooled = (float*)(ws + off); off = align256(off + (size_t)BB * HH * 4);
    float* cnt    = (float*)(ws + off); off = align256(off + (size_t)BB * 4);
    size_t zlen = off - zoff;
    float* dinv   = (float*)(ws + off); off = align256(off + (size_t)(NN + 1) * 4);
    int*   row2   = (int*)(ws + off);   off = align256(off + (size_t)(NN + 1) * 4);
    int*   bsum   = (int*)(ws + off);   off = align256(off + (size_t)NBLK * 4);
    ivec2* pairs  = (ivec2*)(ws + off); off = align256(off + (size_t)8 * CAP * 8);
    int*   esrc2  = (int*)(ws + off);   off = align256(off + ((size_t)EE + 4 * NN + 64) * 4);
    float* bufA   = (float*)(ws + off); off = align256(off + (size_t)8 * CS * 4);
    float* bufB   = (float*)(ws + off); off = align256(off + (size_t)8 * CS * 4);

    detect_i64<<<1, 256, 0, stream>>>(eraw, flag);
    (void)hipMemsetAsync(ws + zoff, 0, zlen, stream);

    // padded CSR build: bucketize -> scan -> prefill -> L2-resident fill
    count_bucket<<<CB_BLK, 256, 0, stream>>>(eraw, flag, degi, bfill, pairs);
    scan1<<<NBLK, 256, 0, stream>>>(degi, row2, bsum, dinv);
    scan2<<<1, 512, 0, stream>>>(bsum);
    scan3<<<NBLK, 256, 0, stream>>>(row2, bsum);
    prefill_shard<<<8 * PRE_PER, 256, 0, stream>>>(row2, degi, esrc2);
    fill_shard2<<<8 * FSB_PER, 256, 0, stream>>>(pairs, bfill, row2, fillc, esrc2);

    // layer 1
    gemm_scaled<1><<<GEMM_BLK, 256, 0, stream>>>(x, W1, dinv, bufA);
    gather8<1><<<GATH_BLK, 256, 0, stream>>>(row2, esrc2, bufA, dinv, b1, bufB);
    // layer 2
    gemm_scaled<0><<<GEMM_BLK, 256, 0, stream>>>(bufB, W2, dinv, bufA);
    gather8<1><<<GATH_BLK, 256, 0, stream>>>(row2, esrc2, bufA, dinv, b2, bufB);
    // layer 3 (no relu)
    gemm_scaled<0><<<GEMM_BLK, 256, 0, stream>>>(bufB, W3, dinv, bufA);
    gather8<0><<<GATH_BLK, 256, 0, stream>>>(row2, esrc2, bufA, dinv, b3, bufB);

    // pool + classifier
    pool_kernel<<<NBLK, 256, 0, stream>>>(bufB, braw, flag, pooled, cnt);
    final_linear<<<1, 512, 0, stream>>>(pooled, cnt, Wl, bl, out);
}